// Round 8
// baseline (194.295 us; speedup 1.0000x reference)
//
#include <hip/hip_runtime.h>
#include <math.h>

#define NPTS 16384
#define NPTS_PAD 16896       // +512 float4 pad per batch for scan prefetch
#define KN 32
#define C 256
#define NQ 8192              // 8 * 1024 queries
#define PF_ELEMS (NQ * C)

#define W1P_ELEMS (3 * 16 * 64 * 8)                 // 24576  (Ktiles=3, Ntiles=16)
#define W2P_ELEMS (8 * 16 * 64 * 8)                 // 65536  (Ktiles=8)
#define WP_ELEMS  (W1P_ELEMS + W2P_ELEMS)           // 90112 halves = 180224 B (16-aligned)
#define XYZW_ELEMS (8 * NPTS_PAD)                   // 135168 float4
#define GLUT_N 512                                  // gelu LUT segments over [-4,4]
#define HSTR 264                                    // halves per H16 row

typedef _Float16 half8 __attribute__((ext_vector_type(8)));
typedef _Float16 half4v __attribute__((ext_vector_type(4)));
typedef _Float16 half2t __attribute__((ext_vector_type(2)));
typedef float f32x4 __attribute__((ext_vector_type(4)));
typedef float f32x2 __attribute__((ext_vector_type(2)));

// packed dual-f32 fma (CDNA v_pk_fma_f32)
__device__ __forceinline__ f32x2 pkfma(f32x2 a, f32x2 b, f32x2 c) {
#if __has_builtin(__builtin_elementwise_fma)
    return __builtin_elementwise_fma(a, b, c);
#else
    f32x2 r;
    r.x = fmaf(a.x, b.x, c.x);
    r.y = fmaf(a.y, b.y, c.y);
    return r;
#endif
}

// GeLU via 512-segment slope/intercept chord LUT of the EXACT erf GeLU.
// index = clamp((y+4)*64, 0, 511); edge segments extend linearly (tails
// of gelu are linear to <1e-3 before f16 rounding). Chord err ~3.4e-5.
// Cost: 3 VALU + 1 L1-resident 8B gather + 1 fma  (no transcendentals).
__device__ __forceinline__ float gelu_lut(float y, const float2* __restrict__ lut) {
    const float ys = __builtin_amdgcn_fmed3f(fmaf(y, 64.0f, 256.0f), 0.0f, 511.0f);
    const float2 ab = lut[(int)ys];
    return fmaf(ab.x, y, ab.y);
}

// ---------------------------------------------------------------------------
// Prep: pack W1 (91x256 + b1 folded at k=91, K-padded to 96) and W2 (256x256)
// into f16 fragment order; pack xyz into float4 (x,y,z,|p|^2) with the EXACT
// rounding sequence the encoder's ball query uses (bit-identical membership);
// fill the 512-entry GeLU chord LUT from exact erf GeLU.
//   flat = ((kt*16 + nt)*64 + lane)*8 + j
//   k = kt*32 + (lane>>4)*8 + j ;  ch = nt*16 + (lane&15)
// ---------------------------------------------------------------------------
__global__ void prep_kernel(const float* __restrict__ W1,
                            const float* __restrict__ b1,
                            const float* __restrict__ W2,
                            const float* __restrict__ xyz,
                            _Float16* __restrict__ wp,
                            float4* __restrict__ xyzw,
                            float2* __restrict__ glut) {
    const int idx = blockIdx.x * 256 + threadIdx.x;   // 0 .. 225791
    if (idx < 96 * 256) {
        const int k = idx >> 8, n = idx & 255;
        const float v = (k < 91) ? W1[k * 256 + n] : ((k == 91) ? b1[n] : 0.0f);
        const int kt = k >> 5, quad = (k >> 3) & 3, j = k & 7;
        const int nt = n >> 4, l15 = n & 15;
        wp[(((kt * 16 + nt) * 64) + quad * 16 + l15) * 8 + j] = (_Float16)v;
    } else if (idx < WP_ELEMS) {
        const int e = idx - 96 * 256;
        const int k = e >> 8, n = e & 255;
        const int kt = k >> 5, quad = (k >> 3) & 3, j = k & 7;
        const int nt = n >> 4, l15 = n & 15;
        wp[W1P_ELEMS + (((kt * 16 + nt) * 64) + quad * 16 + l15) * 8 + j] =
            (_Float16)W2[k * 256 + n];
    } else if (idx < WP_ELEMS + XYZW_ELEMS) {
        const int e  = idx - WP_ELEMS;                // 0 .. 135167
        const int bb = e / NPTS_PAD;
        const int off = e - bb * NPTS_PAD;
        float4 v;
        if (off < NPTS) {
            const float px = xyz[((size_t)bb * NPTS + off) * 3 + 0];
            const float py = xyz[((size_t)bb * NPTS + off) * 3 + 1];
            const float pz = xyz[((size_t)bb * NPTS + off) * 3 + 2];
            const float sp = __fadd_rn(__fadd_rn(__fmul_rn(px, px), __fmul_rn(py, py)),
                                       __fmul_rn(pz, pz));
            v = make_float4(px, py, pz, sp);
        } else {
            v = make_float4(1e9f, 1e9f, 1e9f, 3e18f);  // sentinel pad (never in-ball)
        }
        xyzw[(size_t)bb * NPTS_PAD + off] = v;
    } else {
        const int i = idx - (WP_ELEMS + XYZW_ELEMS);  // 0 .. 511
        if (i < GLUT_N) {
            const float x0 = -4.0f + (float)i * (1.0f / 64.0f);
            const float x1 = x0 + (1.0f / 64.0f);
            const float g0 = 0.5f * x0 * (1.0f + erff(x0 * 0.7071067811865475f));
            const float g1 = 0.5f * x1 * (1.0f + erff(x1 * 0.7071067811865475f));
            const float a  = (g1 - g0) * 64.0f;
            const float bi = fmaf(-a, x0, g0);
            glut[i] = make_float2(a, bi);
        }
    }
}

// ---------------------------------------------------------------------------
// Fused: ball-query + gather/posenc + MLP1(LN,GeLU) + MLP2(LN) + max.
// Round-21 (session R8): LUT GeLU — move trans work off the VALU pipe.
//  * R7 post-mortem: 82.5% combined issue, VALU-bound; GeLU's exp2+rcp
//    transcendentals (quarter-rate, ~8cy each) are ~25% of VALU busy.
//  * GeLU -> 512-segment slope/intercept chord LUT of EXACT erf GeLU in
//    global memory (4KB, L1-resident). 5 VALU + 1 VMEM per eval vs
//    5 VALU + 16 trans-cycles. Numerics IMPROVE (chord err 3.4e-5 vs
//    tanh-approx 3e-4). No LDS impact (stays 40448, 4 blocks/CU).
//  * keeps R1-R7: 2 queries/block, saddr weight loads, packed (x,y,z,|p|^2),
//    branchless posenc, Xs/H16 overlay, packed-f32 epilogues, b2->C-init
//    fold, SALU prefix sums, f32 LN tables in LDS, (256,4).
// No runtime-indexed private arrays (all under full unroll, const indices).
// ---------------------------------------------------------------------------
__global__ void __launch_bounds__(256, 4)
encoder_fused(const float4* __restrict__ xyzw,
              const float* __restrict__ pf,
              const float* __restrict__ ctr,
              const float* __restrict__ g1, const float* __restrict__ be1,
              const float* __restrict__ b2, const float* __restrict__ g2,
              const float* __restrict__ be2,
              const _Float16* __restrict__ w1p,
              const _Float16* __restrict__ w2p,
              const float2* __restrict__ glut,
              float* __restrict__ out0,      // patch_feature [8192][256]
              float* __restrict__ out1) {    // neighbor idx as float [8192][32]
    const int q0 = blockIdx.x * 2;           // queries q0, q0+1 (same batch b)
    const int b = q0 >> 10;
    const int t = threadIdx.x;
    const int w = t >> 6;
    const int lane = t & 63;
    const int quad = lane >> 4;
    const int l15  = lane & 15;

    __shared__ __align__(16) unsigned char H16raw[2][KN * HSTR * 2];  // 33792
    __shared__ __align__(16) float lnpf[4 * 256];                     // 4096: g1,be1,g2,be2 (f32)
    __shared__ __align__(16) float2 sred[2][2][16][4];                // 2048: [qq][mt][l15][w]
    __shared__ int nbr[2][KN];                                        // 256
    __shared__ int wcnt[2][2][2][4];                                  // [par][qq][grp][warp]

    _Float16 (*H16a)[HSTR] = (_Float16(*)[HSTR])H16raw[0];
    _Float16 (*H16b)[HSTR] = (_Float16(*)[HSTR])H16raw[1];
    _Float16 (*Xs0)[104]   = (_Float16(*)[104])H16raw[0];   // OVERLAY
    _Float16 (*Xs1)[104]   = (_Float16(*)[104])H16raw[1];   // OVERLAY
    float* g1f  = lnpf;
    float* be1f = lnpf + 256;
    float* g2f  = lnpf + 512;
    float* be2f = lnpf + 768;

    lnpf[t]       = g1[t];
    lnpf[256 + t] = be1[t];
    lnpf[512 + t] = g2[t];
    lnpf[768 + t] = be2[t];

    // ---- Phase 0: shared ball query for both centers, 512 pts/iter ----
    const float4* xwb = xyzw + (size_t)b * NPTS_PAD;
    const float cxA = ctr[q0 * 3 + 0], cyA = ctr[q0 * 3 + 1], czA = ctr[q0 * 3 + 2];
    const float cxB = ctr[q0 * 3 + 3], cyB = ctr[q0 * 3 + 4], czB = ctr[q0 * 3 + 5];
    const float scA = __fadd_rn(__fadd_rn(__fmul_rn(cxA, cxA), __fmul_rn(cyA, cyA)),
                                __fmul_rn(czA, czA));
    const float scB = __fadd_rn(__fadd_rn(__fmul_rn(cxB, cxB), __fmul_rn(cyB, cyB)),
                                __fmul_rn(czB, czB));

    float4 pw0 = xwb[t];
    float4 pw1 = xwb[256 + t];
    int foundA = 0, foundB = 0;
    int par = 0;
    for (int base = 0; base < NPTS; base += 512) {
        // prefetch next iteration (pad guarantees in-bounds; unused at tail)
        const float4 nx0 = xwb[base + 512 + t];
        const float4 nx1 = xwb[base + 768 + t];

        const float dA0 = __fadd_rn(__fadd_rn(__fmul_rn(cxA, pw0.x), __fmul_rn(cyA, pw0.y)),
                                    __fmul_rn(czA, pw0.z));
        const float sA0 = __fsub_rn(__fadd_rn(scA, pw0.w), __fmul_rn(2.0f, dA0));
        const float dA1 = __fadd_rn(__fadd_rn(__fmul_rn(cxA, pw1.x), __fmul_rn(cyA, pw1.y)),
                                    __fmul_rn(czA, pw1.z));
        const float sA1 = __fsub_rn(__fadd_rn(scA, pw1.w), __fmul_rn(2.0f, dA1));
        const float dB0 = __fadd_rn(__fadd_rn(__fmul_rn(cxB, pw0.x), __fmul_rn(cyB, pw0.y)),
                                    __fmul_rn(czB, pw0.z));
        const float sB0 = __fsub_rn(__fadd_rn(scB, pw0.w), __fmul_rn(2.0f, dB0));
        const float dB1 = __fadd_rn(__fadd_rn(__fmul_rn(cxB, pw1.x), __fmul_rn(cyB, pw1.y)),
                                    __fmul_rn(czB, pw1.z));
        const float sB1 = __fsub_rn(__fadd_rn(scB, pw1.w), __fmul_rn(2.0f, dB1));
        const bool iA0 = (sA0 <= 0.0625f);
        const bool iA1 = (sA1 <= 0.0625f);
        const bool iB0 = (sB0 <= 0.0625f);
        const bool iB1 = (sB1 <= 0.0625f);

        const unsigned long long mA0 = __ballot(iA0);
        const unsigned long long mA1 = __ballot(iA1);
        const unsigned long long mB0 = __ballot(iB0);
        const unsigned long long mB1 = __ballot(iB1);
        if (lane == 0) {
            wcnt[par][0][0][w] = (int)__popcll(mA0);
            wcnt[par][0][1][w] = (int)__popcll(mA1);
            wcnt[par][1][0][w] = (int)__popcll(mB0);
            wcnt[par][1][1][w] = (int)__popcll(mB1);
        }
        __syncthreads();
        const unsigned long long lmask = (1ull << lane) - 1ull;
        {   // query A compaction (counts are wave-uniform -> SALU via rfl)
            const int c00 = __builtin_amdgcn_readfirstlane(wcnt[par][0][0][0]);
            const int c01 = __builtin_amdgcn_readfirstlane(wcnt[par][0][0][1]);
            const int c02 = __builtin_amdgcn_readfirstlane(wcnt[par][0][0][2]);
            const int c03 = __builtin_amdgcn_readfirstlane(wcnt[par][0][0][3]);
            const int c10 = __builtin_amdgcn_readfirstlane(wcnt[par][0][1][0]);
            const int c11 = __builtin_amdgcn_readfirstlane(wcnt[par][0][1][1]);
            const int c12 = __builtin_amdgcn_readfirstlane(wcnt[par][0][1][2]);
            const int c13 = __builtin_amdgcn_readfirstlane(wcnt[par][0][1][3]);
            int pre0 = foundA;
            if (w > 0) pre0 += c00;
            if (w > 1) pre0 += c01;
            if (w > 2) pre0 += c02;
            const int C0 = c00 + c01 + c02 + c03;
            int pre1 = foundA + C0;
            if (w > 0) pre1 += c10;
            if (w > 1) pre1 += c11;
            if (w > 2) pre1 += c12;
            const int pos0 = pre0 + (int)__popcll(mA0 & lmask);
            const int pos1 = pre1 + (int)__popcll(mA1 & lmask);
            if (iA0 && pos0 < KN) nbr[0][pos0] = base + t;
            if (iA1 && pos1 < KN) nbr[0][pos1] = base + 256 + t;
            foundA += C0 + c10 + c11 + c12 + c13;   // block-uniform
        }
        {   // query B compaction
            const int c00 = __builtin_amdgcn_readfirstlane(wcnt[par][1][0][0]);
            const int c01 = __builtin_amdgcn_readfirstlane(wcnt[par][1][0][1]);
            const int c02 = __builtin_amdgcn_readfirstlane(wcnt[par][1][0][2]);
            const int c03 = __builtin_amdgcn_readfirstlane(wcnt[par][1][0][3]);
            const int c10 = __builtin_amdgcn_readfirstlane(wcnt[par][1][1][0]);
            const int c11 = __builtin_amdgcn_readfirstlane(wcnt[par][1][1][1]);
            const int c12 = __builtin_amdgcn_readfirstlane(wcnt[par][1][1][2]);
            const int c13 = __builtin_amdgcn_readfirstlane(wcnt[par][1][1][3]);
            int pre0 = foundB;
            if (w > 0) pre0 += c00;
            if (w > 1) pre0 += c01;
            if (w > 2) pre0 += c02;
            const int C0 = c00 + c01 + c02 + c03;
            int pre1 = foundB + C0;
            if (w > 0) pre1 += c10;
            if (w > 1) pre1 += c11;
            if (w > 2) pre1 += c12;
            const int pos0 = pre0 + (int)__popcll(mB0 & lmask);
            const int pos1 = pre1 + (int)__popcll(mB1 & lmask);
            if (iB0 && pos0 < KN) nbr[1][pos0] = base + t;
            if (iB1 && pos1 < KN) nbr[1][pos1] = base + 256 + t;
            foundB += C0 + c10 + c11 + c12 + c13;   // block-uniform
        }
        par ^= 1;
        if (foundA >= KN && foundB >= KN) break;
        pw0 = nx0;
        pw1 = nx1;
    }
    __syncthreads();                  // nbr visible to all
    const int cntA = (foundA < KN) ? foundA : KN;
    const int cntB = (foundB < KN) ? foundB : KN;
    const int fstA = (cntA > 0) ? nbr[0][0] : NPTS;
    const int fstB = (cntB > 0) ? nbr[1][0] : NPTS;

    if (t < 2 * KN) {
        const int qq = t >> 5, i = t & 31;
        const int cnt = qq ? cntB : cntA;
        const int fst = qq ? fstB : fstA;
        out1[(size_t)(q0 + qq) * KN + i] = (float)((i < cnt) ? nbr[qq][i] : fst);
    }

    // ---- Phase 1: gather + rel + posenc into XsQ (k=91 is 1.0 for b1) ----
    #pragma unroll
    for (int qq = 0; qq < 2; ++qq) {
        const int k  = t >> 3;
        const int tc = t & 7;
        const int cnt = qq ? cntB : cntA;
        const int fst = qq ? fstB : fstA;
        const float ccx = qq ? cxB : cxA;
        const float ccy = qq ? cyB : cyA;
        const float ccz = qq ? czB : czA;
        const int nidx = (k < cnt) ? nbr[qq][k] : fst;
        const int n = (nidx < NPTS) ? nidx : NPTS - 1;   // JAX OOB gather clamp
        const float4 pw = xwb[n];
        const float rx = pw.x - ccx;
        const float ry = pw.y - ccy;
        const float rz = pw.z - ccz;
        const float* pfr = pf + ((size_t)b * NPTS + n) * 64;

        const float4 f0 = *(const float4*)(pfr + tc * 8);
        const float4 f1 = *(const float4*)(pfr + tc * 8 + 4);
        half8 hv;
        hv[0] = (_Float16)f0.x; hv[1] = (_Float16)f0.y;
        hv[2] = (_Float16)f0.z; hv[3] = (_Float16)f0.w;
        hv[4] = (_Float16)f1.x; hv[5] = (_Float16)f1.y;
        hv[6] = (_Float16)f1.z; hv[7] = (_Float16)f1.w;
        if (qq == 0) *(half8*)&Xs0[k][tc * 8] = hv;
        else         *(half8*)&Xs1[k][tc * 8] = hv;

        half4v ov;
        #pragma unroll
        for (int j = 0; j < 4; ++j) {
            const int cm = tc * 4 + j;          // 0..31
            const int jj = cm - 3;
            const int d  = jj >> 3;
            const int mm = jj & 7;
            const float rsel = (d == 0) ? rx : ((d == 1) ? ry : rz);
            const float f2 = __int_as_float(0x3E22F983 + ((mm & 3) << 23));
            const float arg = fmaf(rsel, f2, (mm >= 4) ? 0.25f : 0.0f);
#if __has_builtin(__builtin_amdgcn_sinf)
            const float sv = __builtin_amdgcn_sinf(arg);
#else
            const float sv = __sinf(arg * 6.2831853071795864f);
#endif
            float v = (cm < 3) ? ((cm == 0) ? rx : ((cm == 1) ? ry : rz)) : sv;
            v = (cm == 27) ? 1.0f : ((cm > 27) ? 0.0f : v);
            ov[j] = (_Float16)v;
        }
        if (qq == 0) *(half4v*)&Xs0[k][64 + tc * 4] = ov;
        else         *(half4v*)&Xs1[k][64 + tc * 4] = ov;
    }
    __syncthreads();

    f32x4 acc[2][2][4];   // [qq][mt][nt]; lane: ch=(w*4+nt)*16+quad*4+r, pt=mt*16+l15

    // uniform (SGPR) weight bases + per-lane voffset -> saddr-form loads
    const int wu = __builtin_amdgcn_readfirstlane(w);
    const _Float16* __restrict__ w1w = w1p + (size_t)(wu * 4) * 512;
    const _Float16* __restrict__ w2w = w2p + (size_t)(wu * 4) * 512;
    const int lo8 = lane * 8;

    // ---- GEMM1: W1^T as A, Xs{0,1} as B -> acc (b1 via folded row) ----
    #pragma unroll
    for (int qq = 0; qq < 2; ++qq)
        #pragma unroll
        for (int mt = 0; mt < 2; ++mt)
            #pragma unroll
            for (int nt = 0; nt < 4; ++nt)
                acc[qq][mt][nt] = (f32x4){0.f, 0.f, 0.f, 0.f};

    #pragma unroll
    for (int kt = 0; kt < 3; ++kt) {
        const half8 xA0 = *(const half8*)&Xs0[l15][kt * 32 + quad * 8];
        const half8 xA1 = *(const half8*)&Xs0[16 + l15][kt * 32 + quad * 8];
        const half8 xB0 = *(const half8*)&Xs1[l15][kt * 32 + quad * 8];
        const half8 xB1 = *(const half8*)&Xs1[16 + l15][kt * 32 + quad * 8];
        #pragma unroll
        for (int nt = 0; nt < 4; ++nt) {
            const half8 wf = *(const half8*)(w1w + (kt * 16 + nt) * 512 + lo8);
            acc[0][0][nt] = __builtin_amdgcn_mfma_f32_16x16x32_f16(wf, xA0, acc[0][0][nt], 0, 0, 0);
            acc[0][1][nt] = __builtin_amdgcn_mfma_f32_16x16x32_f16(wf, xA1, acc[0][1][nt], 0, 0, 0);
            acc[1][0][nt] = __builtin_amdgcn_mfma_f32_16x16x32_f16(wf, xB0, acc[1][0][nt], 0, 0, 0);
            acc[1][1][nt] = __builtin_amdgcn_mfma_f32_16x16x32_f16(wf, xB1, acc[1][1][nt], 0, 0, 0);
        }
    }

    // ---- LN1 stats: packed pairwise accumulate + quad shfl + cross-warp LDS ----
    float mu[2][2], rs[2][2];
    #pragma unroll
    for (int qq = 0; qq < 2; ++qq)
        #pragma unroll
        for (int mt = 0; mt < 2; ++mt) {
            f32x2 sx  = {0.f, 0.f};
            f32x2 s2x = {0.f, 0.f};
            #pragma unroll
            for (int nt = 0; nt < 4; ++nt) {
                const f32x4 a4 = acc[qq][mt][nt];
                const f32x2 v0 = __builtin_shufflevector(a4, a4, 0, 1);
                const f32x2 v1 = __builtin_shufflevector(a4, a4, 2, 3);
                sx  = sx + v0;
                sx  = sx + v1;
                s2x = pkfma(v0, v0, s2x);
                s2x = pkfma(v1, v1, s2x);
            }
            float s  = sx.x + sx.y;
            float s2 = s2x.x + s2x.y;
            s  += __shfl_xor(s, 16, 64);  s  += __shfl_xor(s, 32, 64);
            s2 += __shfl_xor(s2, 16, 64); s2 += __shfl_xor(s2, 32, 64);
            if (quad == 0) sred[qq][mt][l15][w] = make_float2(s, s2);
        }
    __syncthreads();   // overlay fence (Xs reads done) + sred partials visible
    #pragma unroll
    for (int qq = 0; qq < 2; ++qq)
        #pragma unroll
        for (int mt = 0; mt < 2; ++mt) {
            const float4 pA = *(const float4*)&sred[qq][mt][l15][0];
            const float4 pB = *(const float4*)&sred[qq][mt][l15][2];
            const float S = pA.x + pA.z + pB.x + pB.z;
            const float Q = pA.y + pA.w + pB.y + pB.w;
            const float m_ = S * (1.0f / 256.0f);
            const float var = fmaf(Q, 1.0f / 256.0f, -m_ * m_);
            mu[qq][mt] = m_;
            rs[qq][mt] = __builtin_amdgcn_rsqf(var + 1e-5f);
        }

    // ---- LN1 apply (packed f32) + LUT GeLU, single f16 store into H16 ----
    #pragma unroll
    for (int nt = 0; nt < 4; ++nt) {
        const int chb = (w * 4 + nt) * 16 + quad * 4;
        const f32x2 gf0 = *(const f32x2*)&g1f[chb];
        const f32x2 gf1 = *(const f32x2*)&g1f[chb + 2];
        const f32x2 bf0 = *(const f32x2*)&be1f[chb];
        const f32x2 bf1 = *(const f32x2*)&be1f[chb + 2];
        #pragma unroll
        for (int qq = 0; qq < 2; ++qq)
            #pragma unroll
            for (int mt = 0; mt < 2; ++mt) {
                const f32x2 rs2  = {rs[qq][mt], rs[qq][mt]};
                const f32x2 nmu2 = {-mu[qq][mt], -mu[qq][mt]};
                const f32x2 A0 = gf0 * rs2;
                const f32x2 A1 = gf1 * rs2;
                const f32x2 B0 = pkfma(nmu2, A0, bf0);
                const f32x2 B1 = pkfma(nmu2, A1, bf1);
                const f32x4 a4 = acc[qq][mt][nt];
                const f32x2 y0 = pkfma(__builtin_shufflevector(a4, a4, 0, 1), A0, B0);
                const f32x2 y1 = pkfma(__builtin_shufflevector(a4, a4, 2, 3), A1, B1);
                half4v h;
                h[0] = (_Float16)gelu_lut(y0.x, glut);
                h[1] = (_Float16)gelu_lut(y0.y, glut);
                h[2] = (_Float16)gelu_lut(y1.x, glut);
                h[3] = (_Float16)gelu_lut(y1.y, glut);
                if (qq == 0) *(half4v*)&H16a[mt * 16 + l15][chb] = h;
                else         *(half4v*)&H16b[mt * 16 + l15][chb] = h;
            }
    }
    __syncthreads();   // H16 ready for GEMM2 B-reads

    // b2 fragments for GEMM2 C-init (short live range: load here, die at init)
    f32x4 bv[4];
    #pragma unroll
    for (int nt = 0; nt < 4; ++nt)
        bv[nt] = *(const f32x4*)&b2[(w * 4 + nt) * 16 + quad * 4];

    // ---- GEMM2: W2^T as A, H{a,b} as B; C-init = b2 (fold) ----
    #pragma unroll
    for (int qq = 0; qq < 2; ++qq)
        #pragma unroll
        for (int mt = 0; mt < 2; ++mt)
            #pragma unroll
            for (int nt = 0; nt < 4; ++nt)
                acc[qq][mt][nt] = bv[nt];

    #pragma unroll
    for (int kt = 0; kt < 8; ++kt) {
        const half8 hA0 = *(const half8*)&H16a[l15][kt * 32 + quad * 8];
        const half8 hA1 = *(const half8*)&H16a[16 + l15][kt * 32 + quad * 8];
        const half8 hB0 = *(const half8*)&H16b[l15][kt * 32 + quad * 8];
        const half8 hB1 = *(const half8*)&H16b[16 + l15][kt * 32 + quad * 8];
        #pragma unroll
        for (int nt = 0; nt < 4; ++nt) {
            const half8 wf = *(const half8*)(w2w + (kt * 16 + nt) * 512 + lo8);
            acc[0][0][nt] = __builtin_amdgcn_mfma_f32_16x16x32_f16(wf, hA0, acc[0][0][nt], 0, 0, 0);
            acc[0][1][nt] = __builtin_amdgcn_mfma_f32_16x16x32_f16(wf, hA1, acc[0][1][nt], 0, 0, 0);
            acc[1][0][nt] = __builtin_amdgcn_mfma_f32_16x16x32_f16(wf, hB0, acc[1][0][nt], 0, 0, 0);
            acc[1][1][nt] = __builtin_amdgcn_mfma_f32_16x16x32_f16(wf, hB1, acc[1][1][nt], 0, 0, 0);
        }
    }

    // ---- LN2 stats: packed pairwise (b2 already folded in) ----
    #pragma unroll
    for (int qq = 0; qq < 2; ++qq)
        #pragma unroll
        for (int mt = 0; mt < 2; ++mt) {
            f32x2 sx  = {0.f, 0.f};
            f32x2 s2x = {0.f, 0.f};
            #pragma unroll
            for (int nt = 0; nt < 4; ++nt) {
                const f32x4 a4 = acc[qq][mt][nt];
                const f32x2 v0 = __builtin_shufflevector(a4, a4, 0, 1);
                const f32x2 v1 = __builtin_shufflevector(a4, a4, 2, 3);
                sx  = sx + v0;
                sx  = sx + v1;
                s2x = pkfma(v0, v0, s2x);
                s2x = pkfma(v1, v1, s2x);
            }
            float s  = sx.x + sx.y;
            float s2 = s2x.x + s2x.y;
            s  += __shfl_xor(s, 16, 64);  s  += __shfl_xor(s, 32, 64);
            s2 += __shfl_xor(s2, 16, 64); s2 += __shfl_xor(s2, 32, 64);
            if (quad == 0) sred[qq][mt][l15][w] = make_float2(s, s2);
        }
    __syncthreads();   // ALL H16 B-reads done (in-place store safe) + partials
    #pragma unroll
    for (int qq = 0; qq < 2; ++qq)
        #pragma unroll
        for (int mt = 0; mt < 2; ++mt) {
            const float4 pA = *(const float4*)&sred[qq][mt][l15][0];
            const float4 pB = *(const float4*)&sred[qq][mt][l15][2];
            const float S = pA.x + pA.z + pB.x + pB.z;
            const float Q = pA.y + pA.w + pB.y + pB.w;
            const float m_ = S * (1.0f / 256.0f);
            const float var = fmaf(Q, 1.0f / 256.0f, -m_ * m_);
            mu[qq][mt] = m_;
            rs[qq][mt] = __builtin_amdgcn_rsqf(var + 1e-5f);
        }

    // ---- LN2 apply (no activation), packed f32, f16 store into H16 ----
    #pragma unroll
    for (int nt = 0; nt < 4; ++nt) {
        const int chb = (w * 4 + nt) * 16 + quad * 4;
        const f32x2 gf0 = *(const f32x2*)&g2f[chb];
        const f32x2 gf1 = *(const f32x2*)&g2f[chb + 2];
        const f32x2 bf0 = *(const f32x2*)&be2f[chb];
        const f32x2 bf1 = *(const f32x2*)&be2f[chb + 2];
        #pragma unroll
        for (int qq = 0; qq < 2; ++qq)
            #pragma unroll
            for (int mt = 0; mt < 2; ++mt) {
                const f32x2 rs2  = {rs[qq][mt], rs[qq][mt]};
                const f32x2 nmu2 = {-mu[qq][mt], -mu[qq][mt]};
                const f32x2 A0 = gf0 * rs2;
                const f32x2 A1 = gf1 * rs2;
                const f32x2 B0 = pkfma(nmu2, A0, bf0);
                const f32x2 B1 = pkfma(nmu2, A1, bf1);
                const f32x4 a4 = acc[qq][mt][nt];
                const f32x2 y0 = pkfma(__builtin_shufflevector(a4, a4, 0, 1), A0, B0);
                const f32x2 y1 = pkfma(__builtin_shufflevector(a4, a4, 2, 3), A1, B1);
                half4v h;
                h[0] = (_Float16)y0.x; h[1] = (_Float16)y0.y;
                h[2] = (_Float16)y1.x; h[3] = (_Float16)y1.y;
                if (qq == 0) *(half4v*)&H16a[mt * 16 + l15][chb] = h;
                else         *(half4v*)&H16b[mt * 16 + l15][chb] = h;
            }
    }
    __syncthreads();

    // ---- Phase 6: packed max over 32 points, all 256 threads (2 queries) ----
    {
        const int qq = t >> 7;
        const int tt = t & 127;
        const _Float16* Hf = qq ? &H16b[0][0] : &H16a[0][0];
        half2t mx = *(const half2t*)(Hf + 2 * tt);
        #pragma unroll
        for (int r = 1; r < KN; ++r) {
            const half2t v = *(const half2t*)(Hf + r * HSTR + 2 * tt);
            mx = __builtin_elementwise_max(mx, v);
        }
        float2 o2;
        o2.x = (float)mx[0];
        o2.y = (float)mx[1];
        *(float2*)&out0[(size_t)(q0 + qq) * C + 2 * tt] = o2;
    }
}

extern "C" void kernel_launch(void* const* d_in, const int* in_sizes, int n_in,
                              void* d_out, int out_size, void* d_ws, size_t ws_size,
                              hipStream_t stream) {
    const float* xyz = (const float*)d_in[0];
    const float* pf  = (const float*)d_in[1];
    const float* ctr = (const float*)d_in[2];
    const float* W1  = (const float*)d_in[3];
    const float* b1  = (const float*)d_in[4];
    const float* g1  = (const float*)d_in[5];
    const float* be1 = (const float*)d_in[6];
    const float* W2  = (const float*)d_in[7];
    const float* b2  = (const float*)d_in[8];
    const float* g2  = (const float*)d_in[9];
    const float* be2 = (const float*)d_in[10];

    float* out = (float*)d_out;
    _Float16* wp = (_Float16*)d_ws;
    float4* xyzw = (float4*)(wp + WP_ELEMS);       // 180224 B offset, 16-aligned
    float2* glut = (float2*)(xyzw + XYZW_ELEMS);   // +2162688 B, 16-aligned; 4 KB

    prep_kernel<<<(WP_ELEMS + XYZW_ELEMS + 512) / 256, 256, 0, stream>>>(
        W1, b1, W2, xyz, wp, xyzw, glut);
    encoder_fused<<<NQ / 2, 256, 0, stream>>>(xyzw, pf, ctr,
                                              g1, be1, b2, g2, be2,
                                              wp, wp + W1P_ELEMS, glut,
                                              out, out + PF_ELEMS);
}

// Round 9
// 188.985 us; speedup vs baseline: 1.0281x; 1.0281x over previous
//
#include <hip/hip_runtime.h>
#include <math.h>

#define NPTS 16384
#define NPTS_PAD 16896       // +512 float4 pad per batch for scan prefetch
#define KN 32
#define C 256
#define NQ 8192              // 8 * 1024 queries
#define PF_ELEMS (NQ * C)

#define W1P_ELEMS (3 * 16 * 64 * 8)                 // 24576  (Ktiles=3, Ntiles=16)
#define W2P_ELEMS (8 * 16 * 64 * 8)                 // 65536  (Ktiles=8)
#define WP_ELEMS  (W1P_ELEMS + W2P_ELEMS)           // 90112 halves = 180224 B (16-aligned)
#define XYZW_ELEMS (8 * NPTS_PAD)                   // 135168 float4
#define HSTR 264                                    // halves per H16 row

typedef _Float16 half8 __attribute__((ext_vector_type(8)));
typedef _Float16 half4v __attribute__((ext_vector_type(4)));
typedef _Float16 half2t __attribute__((ext_vector_type(2)));
typedef float f32x4 __attribute__((ext_vector_type(4)));
typedef float f32x2 __attribute__((ext_vector_type(2)));

__device__ __forceinline__ float exp2f_fast(float x) {
#if __has_builtin(__builtin_amdgcn_exp2f)
    return __builtin_amdgcn_exp2f(x);
#else
    return exp2f(x);
#endif
}

// packed dual-f32 fma (CDNA v_pk_fma_f32)
__device__ __forceinline__ f32x2 pkfma(f32x2 a, f32x2 b, f32x2 c) {
#if __has_builtin(__builtin_elementwise_fma)
    return __builtin_elementwise_fma(a, b, c);
#else
    f32x2 r;
    r.x = fmaf(a.x, b.x, c.x);
    r.y = fmaf(a.y, b.y, c.y);
    return r;
#endif
}

// tanh-approx GeLU on 2 elements: poly part packed (v_pk_*), trans scalar.
// R8 lesson: COMPUTED trans beats LUT gather at 4 blocks/CU — exp2/rcp are
// pipelined on the VALU; a 64-lane divergent gather exposes ~180cy L1 latency
// on the epilogue dependency chain (92.3 -> 117us regression, reverted).
__device__ __forceinline__ f32x2 gelu2(f32x2 y) {
    const f32x2 c1 = {0.10294324f, 0.10294324f};   // 0.07135482 * log2e
    const f32x2 c0 = {2.3022083f, 2.3022083f};     // 1.59576912 * log2e
    const f32x2 t = y * y;
    const f32x2 p = pkfma(t, c1, c0);
    const f32x2 z = y * p;
    const float e0 = exp2f_fast(z.x);
    const float e1 = exp2f_fast(z.y);
    const float r0 = __builtin_amdgcn_rcpf(e0 + 1.0f);
    const float r1 = __builtin_amdgcn_rcpf(e1 + 1.0f);
    f32x2 o;
    o.x = fmaf(-y.x, r0, y.x);
    o.y = fmaf(-y.y, r1, y.y);
    return o;
}

// ---------------------------------------------------------------------------
// Prep: pack W1 (91x256 + b1 folded at k=91, K-padded to 96) and W2 (256x256)
// into f16 fragment order; pack xyz into float4 (x,y,z,|p|^2) with the EXACT
// rounding sequence the encoder's ball query uses (bit-identical membership).
// xyzw is padded per batch to NPTS_PAD (scan prefetch overruns by <=512).
//   flat = ((kt*16 + nt)*64 + lane)*8 + j
//   k = kt*32 + (lane>>4)*8 + j ;  ch = nt*16 + (lane&15)
// ---------------------------------------------------------------------------
__global__ void prep_kernel(const float* __restrict__ W1,
                            const float* __restrict__ b1,
                            const float* __restrict__ W2,
                            const float* __restrict__ xyz,
                            _Float16* __restrict__ wp,
                            float4* __restrict__ xyzw) {
    const int idx = blockIdx.x * 256 + threadIdx.x;   // 0 .. 225279
    if (idx < 96 * 256) {
        const int k = idx >> 8, n = idx & 255;
        const float v = (k < 91) ? W1[k * 256 + n] : ((k == 91) ? b1[n] : 0.0f);
        const int kt = k >> 5, quad = (k >> 3) & 3, j = k & 7;
        const int nt = n >> 4, l15 = n & 15;
        wp[(((kt * 16 + nt) * 64) + quad * 16 + l15) * 8 + j] = (_Float16)v;
    } else if (idx < WP_ELEMS) {
        const int e = idx - 96 * 256;
        const int k = e >> 8, n = e & 255;
        const int kt = k >> 5, quad = (k >> 3) & 3, j = k & 7;
        const int nt = n >> 4, l15 = n & 15;
        wp[W1P_ELEMS + (((kt * 16 + nt) * 64) + quad * 16 + l15) * 8 + j] =
            (_Float16)W2[k * 256 + n];
    } else {
        const int e  = idx - WP_ELEMS;                // 0 .. 135167
        const int bb = e / NPTS_PAD;
        const int off = e - bb * NPTS_PAD;
        float4 v;
        if (off < NPTS) {
            const float px = xyz[((size_t)bb * NPTS + off) * 3 + 0];
            const float py = xyz[((size_t)bb * NPTS + off) * 3 + 1];
            const float pz = xyz[((size_t)bb * NPTS + off) * 3 + 2];
            const float sp = __fadd_rn(__fadd_rn(__fmul_rn(px, px), __fmul_rn(py, py)),
                                       __fmul_rn(pz, pz));
            v = make_float4(px, py, pz, sp);
        } else {
            v = make_float4(1e9f, 1e9f, 1e9f, 3e18f);  // sentinel pad (never in-ball)
        }
        xyzw[(size_t)bb * NPTS_PAD + off] = v;
    }
}

// ---------------------------------------------------------------------------
// Fused: ball-query + gather/posenc + MLP1(LN,GeLU) + MLP2(LN) + max.
// Round-22 (session R9): R7 revert + cross-phase weight prefetch.
//  * R8 post-mortem: LUT GeLU regressed 92.3->117us (divergent gather latency
//    exposed at 4 blocks/CU). Reverted to R7's computed gelu2.
//  * Model: VALUBusy 60% = 40% VALU-idle -> ~60/40 issue/latency bound.
//    Free latency cuts still pay:
//    - GEMM1 kt=0 weight fragments issued at kernel ENTRY (hide L2 latency
//      under the whole ball-query scan; 16 VGPR transient).
//    - GEMM2 kt=0 weight fragments + b2 issued right after GEMM1 (hide under
//      LN1 stats/apply ~1K cycles; 16+16 VGPR transient).
//  * keeps R1-R7: 2 queries/block, saddr weight loads, packed (x,y,z,|p|^2),
//    branchless posenc, Xs/H16 overlay, packed-f32 epilogues, b2->C-init
//    fold, SALU prefix sums, f32 LN tables in LDS, (256,4).
// No runtime-indexed private arrays (all under full unroll, const indices).
// ---------------------------------------------------------------------------
__global__ void __launch_bounds__(256, 4)
encoder_fused(const float4* __restrict__ xyzw,
              const float* __restrict__ pf,
              const float* __restrict__ ctr,
              const float* __restrict__ g1, const float* __restrict__ be1,
              const float* __restrict__ b2, const float* __restrict__ g2,
              const float* __restrict__ be2,
              const _Float16* __restrict__ w1p,
              const _Float16* __restrict__ w2p,
              float* __restrict__ out0,      // patch_feature [8192][256]
              float* __restrict__ out1) {    // neighbor idx as float [8192][32]
    const int q0 = blockIdx.x * 2;           // queries q0, q0+1 (same batch b)
    const int b = q0 >> 10;
    const int t = threadIdx.x;
    const int w = t >> 6;
    const int lane = t & 63;
    const int quad = lane >> 4;
    const int l15  = lane & 15;

    __shared__ __align__(16) unsigned char H16raw[2][KN * HSTR * 2];  // 33792
    __shared__ __align__(16) float lnpf[4 * 256];                     // 4096: g1,be1,g2,be2 (f32)
    __shared__ __align__(16) float2 sred[2][2][16][4];                // 2048: [qq][mt][l15][w]
    __shared__ int nbr[2][KN];                                        // 256
    __shared__ int wcnt[2][2][2][4];                                  // [par][qq][grp][warp]

    _Float16 (*H16a)[HSTR] = (_Float16(*)[HSTR])H16raw[0];
    _Float16 (*H16b)[HSTR] = (_Float16(*)[HSTR])H16raw[1];
    _Float16 (*Xs0)[104]   = (_Float16(*)[104])H16raw[0];   // OVERLAY
    _Float16 (*Xs1)[104]   = (_Float16(*)[104])H16raw[1];   // OVERLAY
    float* g1f  = lnpf;
    float* be1f = lnpf + 256;
    float* g2f  = lnpf + 512;
    float* be2f = lnpf + 768;

    lnpf[t]       = g1[t];
    lnpf[256 + t] = be1[t];
    lnpf[512 + t] = g2[t];
    lnpf[768 + t] = be2[t];

    // uniform (SGPR) weight bases + per-lane voffset -> saddr-form loads.
    // Computed at entry so the GEMM1 kt=0 prefetch can issue before the scan.
    const int wu = __builtin_amdgcn_readfirstlane(w);
    const _Float16* __restrict__ w1w = w1p + (size_t)(wu * 4) * 512;
    const _Float16* __restrict__ w2w = w2p + (size_t)(wu * 4) * 512;
    const int lo8 = lane * 8;

    // ---- GEMM1 kt=0 weight prefetch: L2 latency hides under the scan ----
    half8 w1pre[4];
    #pragma unroll
    for (int nt = 0; nt < 4; ++nt)
        w1pre[nt] = *(const half8*)(w1w + nt * 512 + lo8);

    // ---- Phase 0: shared ball query for both centers, 512 pts/iter ----
    const float4* xwb = xyzw + (size_t)b * NPTS_PAD;
    const float cxA = ctr[q0 * 3 + 0], cyA = ctr[q0 * 3 + 1], czA = ctr[q0 * 3 + 2];
    const float cxB = ctr[q0 * 3 + 3], cyB = ctr[q0 * 3 + 4], czB = ctr[q0 * 3 + 5];
    const float scA = __fadd_rn(__fadd_rn(__fmul_rn(cxA, cxA), __fmul_rn(cyA, cyA)),
                                __fmul_rn(czA, czA));
    const float scB = __fadd_rn(__fadd_rn(__fmul_rn(cxB, cxB), __fmul_rn(cyB, cyB)),
                                __fmul_rn(czB, czB));

    float4 pw0 = xwb[t];
    float4 pw1 = xwb[256 + t];
    int foundA = 0, foundB = 0;
    int par = 0;
    for (int base = 0; base < NPTS; base += 512) {
        // prefetch next iteration (pad guarantees in-bounds; unused at tail)
        const float4 nx0 = xwb[base + 512 + t];
        const float4 nx1 = xwb[base + 768 + t];

        const float dA0 = __fadd_rn(__fadd_rn(__fmul_rn(cxA, pw0.x), __fmul_rn(cyA, pw0.y)),
                                    __fmul_rn(czA, pw0.z));
        const float sA0 = __fsub_rn(__fadd_rn(scA, pw0.w), __fmul_rn(2.0f, dA0));
        const float dA1 = __fadd_rn(__fadd_rn(__fmul_rn(cxA, pw1.x), __fmul_rn(cyA, pw1.y)),
                                    __fmul_rn(czA, pw1.z));
        const float sA1 = __fsub_rn(__fadd_rn(scA, pw1.w), __fmul_rn(2.0f, dA1));
        const float dB0 = __fadd_rn(__fadd_rn(__fmul_rn(cxB, pw0.x), __fmul_rn(cyB, pw0.y)),
                                    __fmul_rn(czB, pw0.z));
        const float sB0 = __fsub_rn(__fadd_rn(scB, pw0.w), __fmul_rn(2.0f, dB0));
        const float dB1 = __fadd_rn(__fadd_rn(__fmul_rn(cxB, pw1.x), __fmul_rn(cyB, pw1.y)),
                                    __fmul_rn(czB, pw1.z));
        const float sB1 = __fsub_rn(__fadd_rn(scB, pw1.w), __fmul_rn(2.0f, dB1));
        const bool iA0 = (sA0 <= 0.0625f);
        const bool iA1 = (sA1 <= 0.0625f);
        const bool iB0 = (sB0 <= 0.0625f);
        const bool iB1 = (sB1 <= 0.0625f);

        const unsigned long long mA0 = __ballot(iA0);
        const unsigned long long mA1 = __ballot(iA1);
        const unsigned long long mB0 = __ballot(iB0);
        const unsigned long long mB1 = __ballot(iB1);
        if (lane == 0) {
            wcnt[par][0][0][w] = (int)__popcll(mA0);
            wcnt[par][0][1][w] = (int)__popcll(mA1);
            wcnt[par][1][0][w] = (int)__popcll(mB0);
            wcnt[par][1][1][w] = (int)__popcll(mB1);
        }
        __syncthreads();
        const unsigned long long lmask = (1ull << lane) - 1ull;
        {   // query A compaction (counts are wave-uniform -> SALU via rfl)
            const int c00 = __builtin_amdgcn_readfirstlane(wcnt[par][0][0][0]);
            const int c01 = __builtin_amdgcn_readfirstlane(wcnt[par][0][0][1]);
            const int c02 = __builtin_amdgcn_readfirstlane(wcnt[par][0][0][2]);
            const int c03 = __builtin_amdgcn_readfirstlane(wcnt[par][0][0][3]);
            const int c10 = __builtin_amdgcn_readfirstlane(wcnt[par][0][1][0]);
            const int c11 = __builtin_amdgcn_readfirstlane(wcnt[par][0][1][1]);
            const int c12 = __builtin_amdgcn_readfirstlane(wcnt[par][0][1][2]);
            const int c13 = __builtin_amdgcn_readfirstlane(wcnt[par][0][1][3]);
            int pre0 = foundA;
            if (w > 0) pre0 += c00;
            if (w > 1) pre0 += c01;
            if (w > 2) pre0 += c02;
            const int C0 = c00 + c01 + c02 + c03;
            int pre1 = foundA + C0;
            if (w > 0) pre1 += c10;
            if (w > 1) pre1 += c11;
            if (w > 2) pre1 += c12;
            const int pos0 = pre0 + (int)__popcll(mA0 & lmask);
            const int pos1 = pre1 + (int)__popcll(mA1 & lmask);
            if (iA0 && pos0 < KN) nbr[0][pos0] = base + t;
            if (iA1 && pos1 < KN) nbr[0][pos1] = base + 256 + t;
            foundA += C0 + c10 + c11 + c12 + c13;   // block-uniform
        }
        {   // query B compaction
            const int c00 = __builtin_amdgcn_readfirstlane(wcnt[par][1][0][0]);
            const int c01 = __builtin_amdgcn_readfirstlane(wcnt[par][1][0][1]);
            const int c02 = __builtin_amdgcn_readfirstlane(wcnt[par][1][0][2]);
            const int c03 = __builtin_amdgcn_readfirstlane(wcnt[par][1][0][3]);
            const int c10 = __builtin_amdgcn_readfirstlane(wcnt[par][1][1][0]);
            const int c11 = __builtin_amdgcn_readfirstlane(wcnt[par][1][1][1]);
            const int c12 = __builtin_amdgcn_readfirstlane(wcnt[par][1][1][2]);
            const int c13 = __builtin_amdgcn_readfirstlane(wcnt[par][1][1][3]);
            int pre0 = foundB;
            if (w > 0) pre0 += c00;
            if (w > 1) pre0 += c01;
            if (w > 2) pre0 += c02;
            const int C0 = c00 + c01 + c02 + c03;
            int pre1 = foundB + C0;
            if (w > 0) pre1 += c10;
            if (w > 1) pre1 += c11;
            if (w > 2) pre1 += c12;
            const int pos0 = pre0 + (int)__popcll(mB0 & lmask);
            const int pos1 = pre1 + (int)__popcll(mB1 & lmask);
            if (iB0 && pos0 < KN) nbr[1][pos0] = base + t;
            if (iB1 && pos1 < KN) nbr[1][pos1] = base + 256 + t;
            foundB += C0 + c10 + c11 + c12 + c13;   // block-uniform
        }
        par ^= 1;
        if (foundA >= KN && foundB >= KN) break;
        pw0 = nx0;
        pw1 = nx1;
    }
    __syncthreads();                  // nbr visible to all
    const int cntA = (foundA < KN) ? foundA : KN;
    const int cntB = (foundB < KN) ? foundB : KN;
    const int fstA = (cntA > 0) ? nbr[0][0] : NPTS;
    const int fstB = (cntB > 0) ? nbr[1][0] : NPTS;

    if (t < 2 * KN) {
        const int qq = t >> 5, i = t & 31;
        const int cnt = qq ? cntB : cntA;
        const int fst = qq ? fstB : fstA;
        out1[(size_t)(q0 + qq) * KN + i] = (float)((i < cnt) ? nbr[qq][i] : fst);
    }

    // ---- Phase 1: gather + rel + posenc into XsQ (k=91 is 1.0 for b1) ----
    #pragma unroll
    for (int qq = 0; qq < 2; ++qq) {
        const int k  = t >> 3;
        const int tc = t & 7;
        const int cnt = qq ? cntB : cntA;
        const int fst = qq ? fstB : fstA;
        const float ccx = qq ? cxB : cxA;
        const float ccy = qq ? cyB : cyA;
        const float ccz = qq ? czB : czA;
        const int nidx = (k < cnt) ? nbr[qq][k] : fst;
        const int n = (nidx < NPTS) ? nidx : NPTS - 1;   // JAX OOB gather clamp
        const float4 pw = xwb[n];
        const float rx = pw.x - ccx;
        const float ry = pw.y - ccy;
        const float rz = pw.z - ccz;
        const float* pfr = pf + ((size_t)b * NPTS + n) * 64;

        const float4 f0 = *(const float4*)(pfr + tc * 8);
        const float4 f1 = *(const float4*)(pfr + tc * 8 + 4);
        half8 hv;
        hv[0] = (_Float16)f0.x; hv[1] = (_Float16)f0.y;
        hv[2] = (_Float16)f0.z; hv[3] = (_Float16)f0.w;
        hv[4] = (_Float16)f1.x; hv[5] = (_Float16)f1.y;
        hv[6] = (_Float16)f1.z; hv[7] = (_Float16)f1.w;
        if (qq == 0) *(half8*)&Xs0[k][tc * 8] = hv;
        else         *(half8*)&Xs1[k][tc * 8] = hv;

        half4v ov;
        #pragma unroll
        for (int j = 0; j < 4; ++j) {
            const int cm = tc * 4 + j;          // 0..31
            const int jj = cm - 3;
            const int d  = jj >> 3;
            const int mm = jj & 7;
            const float rsel = (d == 0) ? rx : ((d == 1) ? ry : rz);
            const float f2 = __int_as_float(0x3E22F983 + ((mm & 3) << 23));
            const float arg = fmaf(rsel, f2, (mm >= 4) ? 0.25f : 0.0f);
#if __has_builtin(__builtin_amdgcn_sinf)
            const float sv = __builtin_amdgcn_sinf(arg);
#else
            const float sv = __sinf(arg * 6.2831853071795864f);
#endif
            float v = (cm < 3) ? ((cm == 0) ? rx : ((cm == 1) ? ry : rz)) : sv;
            v = (cm == 27) ? 1.0f : ((cm > 27) ? 0.0f : v);
            ov[j] = (_Float16)v;
        }
        if (qq == 0) *(half4v*)&Xs0[k][64 + tc * 4] = ov;
        else         *(half4v*)&Xs1[k][64 + tc * 4] = ov;
    }
    __syncthreads();

    f32x4 acc[2][2][4];   // [qq][mt][nt]; lane: ch=(w*4+nt)*16+quad*4+r, pt=mt*16+l15

    // ---- GEMM1: W1^T as A, Xs{0,1} as B -> acc (b1 via folded row) ----
    #pragma unroll
    for (int qq = 0; qq < 2; ++qq)
        #pragma unroll
        for (int mt = 0; mt < 2; ++mt)
            #pragma unroll
            for (int nt = 0; nt < 4; ++nt)
                acc[qq][mt][nt] = (f32x4){0.f, 0.f, 0.f, 0.f};

    #pragma unroll
    for (int kt = 0; kt < 3; ++kt) {
        const half8 xA0 = *(const half8*)&Xs0[l15][kt * 32 + quad * 8];
        const half8 xA1 = *(const half8*)&Xs0[16 + l15][kt * 32 + quad * 8];
        const half8 xB0 = *(const half8*)&Xs1[l15][kt * 32 + quad * 8];
        const half8 xB1 = *(const half8*)&Xs1[16 + l15][kt * 32 + quad * 8];
        #pragma unroll
        for (int nt = 0; nt < 4; ++nt) {
            const half8 wf = (kt == 0) ? w1pre[nt]
                           : *(const half8*)(w1w + (kt * 16 + nt) * 512 + lo8);
            acc[0][0][nt] = __builtin_amdgcn_mfma_f32_16x16x32_f16(wf, xA0, acc[0][0][nt], 0, 0, 0);
            acc[0][1][nt] = __builtin_amdgcn_mfma_f32_16x16x32_f16(wf, xA1, acc[0][1][nt], 0, 0, 0);
            acc[1][0][nt] = __builtin_amdgcn_mfma_f32_16x16x32_f16(wf, xB0, acc[1][0][nt], 0, 0, 0);
            acc[1][1][nt] = __builtin_amdgcn_mfma_f32_16x16x32_f16(wf, xB1, acc[1][1][nt], 0, 0, 0);
        }
    }

    // ---- GEMM2 kt=0 weight + b2 prefetch: hides under LN1 stats/apply ----
    half8 w2pre[4];
    f32x4 bv[4];
    #pragma unroll
    for (int nt = 0; nt < 4; ++nt) {
        w2pre[nt] = *(const half8*)(w2w + nt * 512 + lo8);
        bv[nt] = *(const f32x4*)&b2[(w * 4 + nt) * 16 + quad * 4];
    }

    // ---- LN1 stats: packed pairwise accumulate + quad shfl + cross-warp LDS ----
    float mu[2][2], rs[2][2];
    #pragma unroll
    for (int qq = 0; qq < 2; ++qq)
        #pragma unroll
        for (int mt = 0; mt < 2; ++mt) {
            f32x2 sx  = {0.f, 0.f};
            f32x2 s2x = {0.f, 0.f};
            #pragma unroll
            for (int nt = 0; nt < 4; ++nt) {
                const f32x4 a4 = acc[qq][mt][nt];
                const f32x2 v0 = __builtin_shufflevector(a4, a4, 0, 1);
                const f32x2 v1 = __builtin_shufflevector(a4, a4, 2, 3);
                sx  = sx + v0;
                sx  = sx + v1;
                s2x = pkfma(v0, v0, s2x);
                s2x = pkfma(v1, v1, s2x);
            }
            float s  = sx.x + sx.y;
            float s2 = s2x.x + s2x.y;
            s  += __shfl_xor(s, 16, 64);  s  += __shfl_xor(s, 32, 64);
            s2 += __shfl_xor(s2, 16, 64); s2 += __shfl_xor(s2, 32, 64);
            if (quad == 0) sred[qq][mt][l15][w] = make_float2(s, s2);
        }
    __syncthreads();   // overlay fence (Xs reads done) + sred partials visible
    #pragma unroll
    for (int qq = 0; qq < 2; ++qq)
        #pragma unroll
        for (int mt = 0; mt < 2; ++mt) {
            const float4 pA = *(const float4*)&sred[qq][mt][l15][0];
            const float4 pB = *(const float4*)&sred[qq][mt][l15][2];
            const float S = pA.x + pA.z + pB.x + pB.z;
            const float Q = pA.y + pA.w + pB.y + pB.w;
            const float m_ = S * (1.0f / 256.0f);
            const float var = fmaf(Q, 1.0f / 256.0f, -m_ * m_);
            mu[qq][mt] = m_;
            rs[qq][mt] = __builtin_amdgcn_rsqf(var + 1e-5f);
        }

    // ---- LN1 apply + GeLU, packed f32, single f16 store into H16 ----
    #pragma unroll
    for (int nt = 0; nt < 4; ++nt) {
        const int chb = (w * 4 + nt) * 16 + quad * 4;
        const f32x2 gf0 = *(const f32x2*)&g1f[chb];
        const f32x2 gf1 = *(const f32x2*)&g1f[chb + 2];
        const f32x2 bf0 = *(const f32x2*)&be1f[chb];
        const f32x2 bf1 = *(const f32x2*)&be1f[chb + 2];
        #pragma unroll
        for (int qq = 0; qq < 2; ++qq)
            #pragma unroll
            for (int mt = 0; mt < 2; ++mt) {
                const f32x2 rs2  = {rs[qq][mt], rs[qq][mt]};
                const f32x2 nmu2 = {-mu[qq][mt], -mu[qq][mt]};
                const f32x2 A0 = gf0 * rs2;
                const f32x2 A1 = gf1 * rs2;
                const f32x2 B0 = pkfma(nmu2, A0, bf0);
                const f32x2 B1 = pkfma(nmu2, A1, bf1);
                const f32x4 a4 = acc[qq][mt][nt];
                const f32x2 y0 = pkfma(__builtin_shufflevector(a4, a4, 0, 1), A0, B0);
                const f32x2 y1 = pkfma(__builtin_shufflevector(a4, a4, 2, 3), A1, B1);
                const f32x2 o0 = gelu2(y0);
                const f32x2 o1 = gelu2(y1);
                half4v h;
                h[0] = (_Float16)o0.x; h[1] = (_Float16)o0.y;
                h[2] = (_Float16)o1.x; h[3] = (_Float16)o1.y;
                if (qq == 0) *(half4v*)&H16a[mt * 16 + l15][chb] = h;
                else         *(half4v*)&H16b[mt * 16 + l15][chb] = h;
            }
    }
    __syncthreads();   // H16 ready for GEMM2 B-reads

    // ---- GEMM2: W2^T as A, H{a,b} as B; C-init = b2 (fold) ----
    #pragma unroll
    for (int qq = 0; qq < 2; ++qq)
        #pragma unroll
        for (int mt = 0; mt < 2; ++mt)
            #pragma unroll
            for (int nt = 0; nt < 4; ++nt)
                acc[qq][mt][nt] = bv[nt];

    #pragma unroll
    for (int kt = 0; kt < 8; ++kt) {
        const half8 hA0 = *(const half8*)&H16a[l15][kt * 32 + quad * 8];
        const half8 hA1 = *(const half8*)&H16a[16 + l15][kt * 32 + quad * 8];
        const half8 hB0 = *(const half8*)&H16b[l15][kt * 32 + quad * 8];
        const half8 hB1 = *(const half8*)&H16b[16 + l15][kt * 32 + quad * 8];
        #pragma unroll
        for (int nt = 0; nt < 4; ++nt) {
            const half8 wf = (kt == 0) ? w2pre[nt]
                           : *(const half8*)(w2w + (kt * 16 + nt) * 512 + lo8);
            acc[0][0][nt] = __builtin_amdgcn_mfma_f32_16x16x32_f16(wf, hA0, acc[0][0][nt], 0, 0, 0);
            acc[0][1][nt] = __builtin_amdgcn_mfma_f32_16x16x32_f16(wf, hA1, acc[0][1][nt], 0, 0, 0);
            acc[1][0][nt] = __builtin_amdgcn_mfma_f32_16x16x32_f16(wf, hB0, acc[1][0][nt], 0, 0, 0);
            acc[1][1][nt] = __builtin_amdgcn_mfma_f32_16x16x32_f16(wf, hB1, acc[1][1][nt], 0, 0, 0);
        }
    }

    // ---- LN2 stats: packed pairwise (b2 already folded in) ----
    #pragma unroll
    for (int qq = 0; qq < 2; ++qq)
        #pragma unroll
        for (int mt = 0; mt < 2; ++mt) {
            f32x2 sx  = {0.f, 0.f};
            f32x2 s2x = {0.f, 0.f};
            #pragma unroll
            for (int nt = 0; nt < 4; ++nt) {
                const f32x4 a4 = acc[qq][mt][nt];
                const f32x2 v0 = __builtin_shufflevector(a4, a4, 0, 1);
                const f32x2 v1 = __builtin_shufflevector(a4, a4, 2, 3);
                sx  = sx + v0;
                sx  = sx + v1;
                s2x = pkfma(v0, v0, s2x);
                s2x = pkfma(v1, v1, s2x);
            }
            float s  = sx.x + sx.y;
            float s2 = s2x.x + s2x.y;
            s  += __shfl_xor(s, 16, 64);  s  += __shfl_xor(s, 32, 64);
            s2 += __shfl_xor(s2, 16, 64); s2 += __shfl_xor(s2, 32, 64);
            if (quad == 0) sred[qq][mt][l15][w] = make_float2(s, s2);
        }
    __syncthreads();   // ALL H16 B-reads done (in-place store safe) + partials
    #pragma unroll
    for (int qq = 0; qq < 2; ++qq)
        #pragma unroll
        for (int mt = 0; mt < 2; ++mt) {
            const float4 pA = *(const float4*)&sred[qq][mt][l15][0];
            const float4 pB = *(const float4*)&sred[qq][mt][l15][2];
            const float S = pA.x + pA.z + pB.x + pB.z;
            const float Q = pA.y + pA.w + pB.y + pB.w;
            const float m_ = S * (1.0f / 256.0f);
            const float var = fmaf(Q, 1.0f / 256.0f, -m_ * m_);
            mu[qq][mt] = m_;
            rs[qq][mt] = __builtin_amdgcn_rsqf(var + 1e-5f);
        }

    // ---- LN2 apply (no activation), packed f32, f16 store into H16 ----
    #pragma unroll
    for (int nt = 0; nt < 4; ++nt) {
        const int chb = (w * 4 + nt) * 16 + quad * 4;
        const f32x2 gf0 = *(const f32x2*)&g2f[chb];
        const f32x2 gf1 = *(const f32x2*)&g2f[chb + 2];
        const f32x2 bf0 = *(const f32x2*)&be2f[chb];
        const f32x2 bf1 = *(const f32x2*)&be2f[chb + 2];
        #pragma unroll
        for (int qq = 0; qq < 2; ++qq)
            #pragma unroll
            for (int mt = 0; mt < 2; ++mt) {
                const f32x2 rs2  = {rs[qq][mt], rs[qq][mt]};
                const f32x2 nmu2 = {-mu[qq][mt], -mu[qq][mt]};
                const f32x2 A0 = gf0 * rs2;
                const f32x2 A1 = gf1 * rs2;
                const f32x2 B0 = pkfma(nmu2, A0, bf0);
                const f32x2 B1 = pkfma(nmu2, A1, bf1);
                const f32x4 a4 = acc[qq][mt][nt];
                const f32x2 y0 = pkfma(__builtin_shufflevector(a4, a4, 0, 1), A0, B0);
                const f32x2 y1 = pkfma(__builtin_shufflevector(a4, a4, 2, 3), A1, B1);
                half4v h;
                h[0] = (_Float16)y0.x; h[1] = (_Float16)y0.y;
                h[2] = (_Float16)y1.x; h[3] = (_Float16)y1.y;
                if (qq == 0) *(half4v*)&H16a[mt * 16 + l15][chb] = h;
                else         *(half4v*)&H16b[mt * 16 + l15][chb] = h;
            }
    }
    __syncthreads();

    // ---- Phase 6: packed max over 32 points, all 256 threads (2 queries) ----
    {
        const int qq = t >> 7;
        const int tt = t & 127;
        const _Float16* Hf = qq ? &H16b[0][0] : &H16a[0][0];
        half2t mx = *(const half2t*)(Hf + 2 * tt);
        #pragma unroll
        for (int r = 1; r < KN; ++r) {
            const half2t v = *(const half2t*)(Hf + r * HSTR + 2 * tt);
            mx = __builtin_elementwise_max(mx, v);
        }
        float2 o2;
        o2.x = (float)mx[0];
        o2.y = (float)mx[1];
        *(float2*)&out0[(size_t)(q0 + qq) * C + 2 * tt] = o2;
    }
}

extern "C" void kernel_launch(void* const* d_in, const int* in_sizes, int n_in,
                              void* d_out, int out_size, void* d_ws, size_t ws_size,
                              hipStream_t stream) {
    const float* xyz = (const float*)d_in[0];
    const float* pf  = (const float*)d_in[1];
    const float* ctr = (const float*)d_in[2];
    const float* W1  = (const float*)d_in[3];
    const float* b1  = (const float*)d_in[4];
    const float* g1  = (const float*)d_in[5];
    const float* be1 = (const float*)d_in[6];
    const float* W2  = (const float*)d_in[7];
    const float* b2  = (const float*)d_in[8];
    const float* g2  = (const float*)d_in[9];
    const float* be2 = (const float*)d_in[10];

    float* out = (float*)d_out;
    _Float16* wp = (_Float16*)d_ws;
    float4* xyzw = (float4*)(wp + WP_ELEMS);   // 180224 B offset, 16-aligned; +2.06 MB

    prep_kernel<<<(WP_ELEMS + XYZW_ELEMS) / 256, 256, 0, stream>>>(W1, b1, W2, xyz, wp, xyzw);
    encoder_fused<<<NQ / 2, 256, 0, stream>>>(xyzw, pf, ctr,
                                              g1, be1, b2, g2, be2,
                                              wp, wp + W1P_ELEMS,
                                              out, out + PF_ELEMS);
}

// Round 10
// 174.049 us; speedup vs baseline: 1.1163x; 1.0858x over previous
//
#include <hip/hip_runtime.h>
#include <math.h>

#define NPTS 16384
#define NPTS_PAD 16896       // +512 float4 pad per batch for scan prefetch
#define KN 32
#define C 256
#define NQ 8192              // 8 * 1024 queries
#define PF_ELEMS (NQ * C)

#define W1P_ELEMS (3 * 16 * 64 * 8)                 // 24576  (Ktiles=3, Ntiles=16)
#define W2P_ELEMS (8 * 16 * 64 * 8)                 // 65536  (Ktiles=8)
#define WP_ELEMS  (W1P_ELEMS + W2P_ELEMS)           // 90112 halves = 180224 B (16-aligned)
#define XYZW_ELEMS (8 * NPTS_PAD)                   // 135168 float4
#define HSTR 264                                    // halves per H16 row

typedef _Float16 half8 __attribute__((ext_vector_type(8)));
typedef _Float16 half4v __attribute__((ext_vector_type(4)));
typedef _Float16 half2t __attribute__((ext_vector_type(2)));
typedef float f32x4 __attribute__((ext_vector_type(4)));
typedef float f32x2 __attribute__((ext_vector_type(2)));

__device__ __forceinline__ float exp2f_fast(float x) {
#if __has_builtin(__builtin_amdgcn_exp2f)
    return __builtin_amdgcn_exp2f(x);
#else
    return exp2f(x);
#endif
}

// packed dual-f32 fma (CDNA v_pk_fma_f32)
__device__ __forceinline__ f32x2 pkfma(f32x2 a, f32x2 b, f32x2 c) {
#if __has_builtin(__builtin_elementwise_fma)
    return __builtin_elementwise_fma(a, b, c);
#else
    f32x2 r;
    r.x = fmaf(a.x, b.x, c.x);
    r.y = fmaf(a.y, b.y, c.y);
    return r;
#endif
}

// tanh-approx GeLU on 2 elements: poly part packed (v_pk_*), trans scalar.
// R8 lesson: COMPUTED trans beats LUT gather at 4 blocks/CU (LUT: 92->117us).
// R5/R9 lesson: no value may be held across a loop or long region (spills).
__device__ __forceinline__ f32x2 gelu2(f32x2 y) {
    const f32x2 c1 = {0.10294324f, 0.10294324f};   // 0.07135482 * log2e
    const f32x2 c0 = {2.3022083f, 2.3022083f};     // 1.59576912 * log2e
    const f32x2 t = y * y;
    const f32x2 p = pkfma(t, c1, c0);
    const f32x2 z = y * p;
    const float e0 = exp2f_fast(z.x);
    const float e1 = exp2f_fast(z.y);
    const float r0 = __builtin_amdgcn_rcpf(e0 + 1.0f);
    const float r1 = __builtin_amdgcn_rcpf(e1 + 1.0f);
    f32x2 o;
    o.x = fmaf(-y.x, r0, y.x);
    o.y = fmaf(-y.y, r1, y.y);
    return o;
}

// ---------------------------------------------------------------------------
// Prep: pack W1 (91x256 + b1 folded at k=91, K-padded to 96) and W2 (256x256)
// into f16 fragment order; pack xyz into float4 (x,y,z,|p|^2) with the EXACT
// rounding sequence the encoder's ball query uses (bit-identical membership).
// xyzw is padded per batch to NPTS_PAD (scan prefetch overruns by <=512).
//   flat = ((kt*16 + nt)*64 + lane)*8 + j
//   k = kt*32 + (lane>>4)*8 + j ;  ch = nt*16 + (lane&15)
// ---------------------------------------------------------------------------
__global__ void prep_kernel(const float* __restrict__ W1,
                            const float* __restrict__ b1,
                            const float* __restrict__ W2,
                            const float* __restrict__ xyz,
                            _Float16* __restrict__ wp,
                            float4* __restrict__ xyzw) {
    const int idx = blockIdx.x * 256 + threadIdx.x;   // 0 .. 225279
    if (idx < 96 * 256) {
        const int k = idx >> 8, n = idx & 255;
        const float v = (k < 91) ? W1[k * 256 + n] : ((k == 91) ? b1[n] : 0.0f);
        const int kt = k >> 5, quad = (k >> 3) & 3, j = k & 7;
        const int nt = n >> 4, l15 = n & 15;
        wp[(((kt * 16 + nt) * 64) + quad * 16 + l15) * 8 + j] = (_Float16)v;
    } else if (idx < WP_ELEMS) {
        const int e = idx - 96 * 256;
        const int k = e >> 8, n = e & 255;
        const int kt = k >> 5, quad = (k >> 3) & 3, j = k & 7;
        const int nt = n >> 4, l15 = n & 15;
        wp[W1P_ELEMS + (((kt * 16 + nt) * 64) + quad * 16 + l15) * 8 + j] =
            (_Float16)W2[k * 256 + n];
    } else {
        const int e  = idx - WP_ELEMS;                // 0 .. 135167
        const int bb = e / NPTS_PAD;
        const int off = e - bb * NPTS_PAD;
        float4 v;
        if (off < NPTS) {
            const float px = xyz[((size_t)bb * NPTS + off) * 3 + 0];
            const float py = xyz[((size_t)bb * NPTS + off) * 3 + 1];
            const float pz = xyz[((size_t)bb * NPTS + off) * 3 + 2];
            const float sp = __fadd_rn(__fadd_rn(__fmul_rn(px, px), __fmul_rn(py, py)),
                                       __fmul_rn(pz, pz));
            v = make_float4(px, py, pz, sp);
        } else {
            v = make_float4(1e9f, 1e9f, 1e9f, 3e18f);  // sentinel pad (never in-ball)
        }
        xyzw[(size_t)bb * NPTS_PAD + off] = v;
    }
}

// ---------------------------------------------------------------------------
// Fused: ball-query + gather/posenc + MLP1(LN,GeLU) + MLP2(LN) + max.
// Round-23 (session R10): exact R7 revert (proven 92.3us encoder) + setprio
// around the MFMA k-loops.
//  * R9 post-mortem: cross-phase weight prefetch spilled (WRITE 9.2->90MB,
//    108us). Values held across the scan loop / LN1 region spill — the
//    latency-for-register trade is closed on this kernel.
//  * s_setprio(1) around GEMM loops: 4 INDEPENDENT blocks/CU sit at
//    different phases (scan/epilogue/GEMM) -> GEMM-phase waves win issue
//    arbitration over other blocks' VALU phases (T5 precondition = phase
//    diversity, per m191; zero registers, zero structural risk).
//  * keeps R1-R7: 2 queries/block, saddr weight loads, packed (x,y,z,|p|^2),
//    branchless posenc, Xs/H16 overlay, packed-f32 epilogues, b2->C-init
//    fold (loaded AFTER the LN1-store barrier), SALU prefix sums, f32 LN
//    tables in LDS, (256,4).
// No runtime-indexed private arrays (all under full unroll, const indices).
// ---------------------------------------------------------------------------
__global__ void __launch_bounds__(256, 4)
encoder_fused(const float4* __restrict__ xyzw,
              const float* __restrict__ pf,
              const float* __restrict__ ctr,
              const float* __restrict__ g1, const float* __restrict__ be1,
              const float* __restrict__ b2, const float* __restrict__ g2,
              const float* __restrict__ be2,
              const _Float16* __restrict__ w1p,
              const _Float16* __restrict__ w2p,
              float* __restrict__ out0,      // patch_feature [8192][256]
              float* __restrict__ out1) {    // neighbor idx as float [8192][32]
    const int q0 = blockIdx.x * 2;           // queries q0, q0+1 (same batch b)
    const int b = q0 >> 10;
    const int t = threadIdx.x;
    const int w = t >> 6;
    const int lane = t & 63;
    const int quad = lane >> 4;
    const int l15  = lane & 15;

    __shared__ __align__(16) unsigned char H16raw[2][KN * HSTR * 2];  // 33792
    __shared__ __align__(16) float lnpf[4 * 256];                     // 4096: g1,be1,g2,be2 (f32)
    __shared__ __align__(16) float2 sred[2][2][16][4];                // 2048: [qq][mt][l15][w]
    __shared__ int nbr[2][KN];                                        // 256
    __shared__ int wcnt[2][2][2][4];                                  // [par][qq][grp][warp]

    _Float16 (*H16a)[HSTR] = (_Float16(*)[HSTR])H16raw[0];
    _Float16 (*H16b)[HSTR] = (_Float16(*)[HSTR])H16raw[1];
    _Float16 (*Xs0)[104]   = (_Float16(*)[104])H16raw[0];   // OVERLAY
    _Float16 (*Xs1)[104]   = (_Float16(*)[104])H16raw[1];   // OVERLAY
    float* g1f  = lnpf;
    float* be1f = lnpf + 256;
    float* g2f  = lnpf + 512;
    float* be2f = lnpf + 768;

    lnpf[t]       = g1[t];
    lnpf[256 + t] = be1[t];
    lnpf[512 + t] = g2[t];
    lnpf[768 + t] = be2[t];

    // ---- Phase 0: shared ball query for both centers, 512 pts/iter ----
    const float4* xwb = xyzw + (size_t)b * NPTS_PAD;
    const float cxA = ctr[q0 * 3 + 0], cyA = ctr[q0 * 3 + 1], czA = ctr[q0 * 3 + 2];
    const float cxB = ctr[q0 * 3 + 3], cyB = ctr[q0 * 3 + 4], czB = ctr[q0 * 3 + 5];
    const float scA = __fadd_rn(__fadd_rn(__fmul_rn(cxA, cxA), __fmul_rn(cyA, cyA)),
                                __fmul_rn(czA, czA));
    const float scB = __fadd_rn(__fadd_rn(__fmul_rn(cxB, cxB), __fmul_rn(cyB, cyB)),
                                __fmul_rn(czB, czB));

    float4 pw0 = xwb[t];
    float4 pw1 = xwb[256 + t];
    int foundA = 0, foundB = 0;
    int par = 0;
    for (int base = 0; base < NPTS; base += 512) {
        // prefetch next iteration (pad guarantees in-bounds; unused at tail)
        const float4 nx0 = xwb[base + 512 + t];
        const float4 nx1 = xwb[base + 768 + t];

        const float dA0 = __fadd_rn(__fadd_rn(__fmul_rn(cxA, pw0.x), __fmul_rn(cyA, pw0.y)),
                                    __fmul_rn(czA, pw0.z));
        const float sA0 = __fsub_rn(__fadd_rn(scA, pw0.w), __fmul_rn(2.0f, dA0));
        const float dA1 = __fadd_rn(__fadd_rn(__fmul_rn(cxA, pw1.x), __fmul_rn(cyA, pw1.y)),
                                    __fmul_rn(czA, pw1.z));
        const float sA1 = __fsub_rn(__fadd_rn(scA, pw1.w), __fmul_rn(2.0f, dA1));
        const float dB0 = __fadd_rn(__fadd_rn(__fmul_rn(cxB, pw0.x), __fmul_rn(cyB, pw0.y)),
                                    __fmul_rn(czB, pw0.z));
        const float sB0 = __fsub_rn(__fadd_rn(scB, pw0.w), __fmul_rn(2.0f, dB0));
        const float dB1 = __fadd_rn(__fadd_rn(__fmul_rn(cxB, pw1.x), __fmul_rn(cyB, pw1.y)),
                                    __fmul_rn(czB, pw1.z));
        const float sB1 = __fsub_rn(__fadd_rn(scB, pw1.w), __fmul_rn(2.0f, dB1));
        const bool iA0 = (sA0 <= 0.0625f);
        const bool iA1 = (sA1 <= 0.0625f);
        const bool iB0 = (sB0 <= 0.0625f);
        const bool iB1 = (sB1 <= 0.0625f);

        const unsigned long long mA0 = __ballot(iA0);
        const unsigned long long mA1 = __ballot(iA1);
        const unsigned long long mB0 = __ballot(iB0);
        const unsigned long long mB1 = __ballot(iB1);
        if (lane == 0) {
            wcnt[par][0][0][w] = (int)__popcll(mA0);
            wcnt[par][0][1][w] = (int)__popcll(mA1);
            wcnt[par][1][0][w] = (int)__popcll(mB0);
            wcnt[par][1][1][w] = (int)__popcll(mB1);
        }
        __syncthreads();
        const unsigned long long lmask = (1ull << lane) - 1ull;
        {   // query A compaction (counts are wave-uniform -> SALU via rfl)
            const int c00 = __builtin_amdgcn_readfirstlane(wcnt[par][0][0][0]);
            const int c01 = __builtin_amdgcn_readfirstlane(wcnt[par][0][0][1]);
            const int c02 = __builtin_amdgcn_readfirstlane(wcnt[par][0][0][2]);
            const int c03 = __builtin_amdgcn_readfirstlane(wcnt[par][0][0][3]);
            const int c10 = __builtin_amdgcn_readfirstlane(wcnt[par][0][1][0]);
            const int c11 = __builtin_amdgcn_readfirstlane(wcnt[par][0][1][1]);
            const int c12 = __builtin_amdgcn_readfirstlane(wcnt[par][0][1][2]);
            const int c13 = __builtin_amdgcn_readfirstlane(wcnt[par][0][1][3]);
            int pre0 = foundA;
            if (w > 0) pre0 += c00;
            if (w > 1) pre0 += c01;
            if (w > 2) pre0 += c02;
            const int C0 = c00 + c01 + c02 + c03;
            int pre1 = foundA + C0;
            if (w > 0) pre1 += c10;
            if (w > 1) pre1 += c11;
            if (w > 2) pre1 += c12;
            const int pos0 = pre0 + (int)__popcll(mA0 & lmask);
            const int pos1 = pre1 + (int)__popcll(mA1 & lmask);
            if (iA0 && pos0 < KN) nbr[0][pos0] = base + t;
            if (iA1 && pos1 < KN) nbr[0][pos1] = base + 256 + t;
            foundA += C0 + c10 + c11 + c12 + c13;   // block-uniform
        }
        {   // query B compaction
            const int c00 = __builtin_amdgcn_readfirstlane(wcnt[par][1][0][0]);
            const int c01 = __builtin_amdgcn_readfirstlane(wcnt[par][1][0][1]);
            const int c02 = __builtin_amdgcn_readfirstlane(wcnt[par][1][0][2]);
            const int c03 = __builtin_amdgcn_readfirstlane(wcnt[par][1][0][3]);
            const int c10 = __builtin_amdgcn_readfirstlane(wcnt[par][1][1][0]);
            const int c11 = __builtin_amdgcn_readfirstlane(wcnt[par][1][1][1]);
            const int c12 = __builtin_amdgcn_readfirstlane(wcnt[par][1][1][2]);
            const int c13 = __builtin_amdgcn_readfirstlane(wcnt[par][1][1][3]);
            int pre0 = foundB;
            if (w > 0) pre0 += c00;
            if (w > 1) pre0 += c01;
            if (w > 2) pre0 += c02;
            const int C0 = c00 + c01 + c02 + c03;
            int pre1 = foundB + C0;
            if (w > 0) pre1 += c10;
            if (w > 1) pre1 += c11;
            if (w > 2) pre1 += c12;
            const int pos0 = pre0 + (int)__popcll(mB0 & lmask);
            const int pos1 = pre1 + (int)__popcll(mB1 & lmask);
            if (iB0 && pos0 < KN) nbr[1][pos0] = base + t;
            if (iB1 && pos1 < KN) nbr[1][pos1] = base + 256 + t;
            foundB += C0 + c10 + c11 + c12 + c13;   // block-uniform
        }
        par ^= 1;
        if (foundA >= KN && foundB >= KN) break;
        pw0 = nx0;
        pw1 = nx1;
    }
    __syncthreads();                  // nbr visible to all
    const int cntA = (foundA < KN) ? foundA : KN;
    const int cntB = (foundB < KN) ? foundB : KN;
    const int fstA = (cntA > 0) ? nbr[0][0] : NPTS;
    const int fstB = (cntB > 0) ? nbr[1][0] : NPTS;

    if (t < 2 * KN) {
        const int qq = t >> 5, i = t & 31;
        const int cnt = qq ? cntB : cntA;
        const int fst = qq ? fstB : fstA;
        out1[(size_t)(q0 + qq) * KN + i] = (float)((i < cnt) ? nbr[qq][i] : fst);
    }

    // ---- Phase 1: gather + rel + posenc into XsQ (k=91 is 1.0 for b1) ----
    #pragma unroll
    for (int qq = 0; qq < 2; ++qq) {
        const int k  = t >> 3;
        const int tc = t & 7;
        const int cnt = qq ? cntB : cntA;
        const int fst = qq ? fstB : fstA;
        const float ccx = qq ? cxB : cxA;
        const float ccy = qq ? cyB : cyA;
        const float ccz = qq ? czB : czA;
        const int nidx = (k < cnt) ? nbr[qq][k] : fst;
        const int n = (nidx < NPTS) ? nidx : NPTS - 1;   // JAX OOB gather clamp
        const float4 pw = xwb[n];
        const float rx = pw.x - ccx;
        const float ry = pw.y - ccy;
        const float rz = pw.z - ccz;
        const float* pfr = pf + ((size_t)b * NPTS + n) * 64;

        const float4 f0 = *(const float4*)(pfr + tc * 8);
        const float4 f1 = *(const float4*)(pfr + tc * 8 + 4);
        half8 hv;
        hv[0] = (_Float16)f0.x; hv[1] = (_Float16)f0.y;
        hv[2] = (_Float16)f0.z; hv[3] = (_Float16)f0.w;
        hv[4] = (_Float16)f1.x; hv[5] = (_Float16)f1.y;
        hv[6] = (_Float16)f1.z; hv[7] = (_Float16)f1.w;
        if (qq == 0) *(half8*)&Xs0[k][tc * 8] = hv;
        else         *(half8*)&Xs1[k][tc * 8] = hv;

        half4v ov;
        #pragma unroll
        for (int j = 0; j < 4; ++j) {
            const int cm = tc * 4 + j;          // 0..31
            const int jj = cm - 3;
            const int d  = jj >> 3;
            const int mm = jj & 7;
            const float rsel = (d == 0) ? rx : ((d == 1) ? ry : rz);
            const float f2 = __int_as_float(0x3E22F983 + ((mm & 3) << 23));
            const float arg = fmaf(rsel, f2, (mm >= 4) ? 0.25f : 0.0f);
#if __has_builtin(__builtin_amdgcn_sinf)
            const float sv = __builtin_amdgcn_sinf(arg);
#else
            const float sv = __sinf(arg * 6.2831853071795864f);
#endif
            float v = (cm < 3) ? ((cm == 0) ? rx : ((cm == 1) ? ry : rz)) : sv;
            v = (cm == 27) ? 1.0f : ((cm > 27) ? 0.0f : v);
            ov[j] = (_Float16)v;
        }
        if (qq == 0) *(half4v*)&Xs0[k][64 + tc * 4] = ov;
        else         *(half4v*)&Xs1[k][64 + tc * 4] = ov;
    }
    __syncthreads();

    f32x4 acc[2][2][4];   // [qq][mt][nt]; lane: ch=(w*4+nt)*16+quad*4+r, pt=mt*16+l15

    // uniform (SGPR) weight bases + per-lane voffset -> saddr-form loads
    const int wu = __builtin_amdgcn_readfirstlane(w);
    const _Float16* __restrict__ w1w = w1p + (size_t)(wu * 4) * 512;
    const _Float16* __restrict__ w2w = w2p + (size_t)(wu * 4) * 512;
    const int lo8 = lane * 8;

    // ---- GEMM1: W1^T as A, Xs{0,1} as B -> acc (b1 via folded row) ----
    #pragma unroll
    for (int qq = 0; qq < 2; ++qq)
        #pragma unroll
        for (int mt = 0; mt < 2; ++mt)
            #pragma unroll
            for (int nt = 0; nt < 4; ++nt)
                acc[qq][mt][nt] = (f32x4){0.f, 0.f, 0.f, 0.f};

    __builtin_amdgcn_s_setprio(1);
    #pragma unroll
    for (int kt = 0; kt < 3; ++kt) {
        const half8 xA0 = *(const half8*)&Xs0[l15][kt * 32 + quad * 8];
        const half8 xA1 = *(const half8*)&Xs0[16 + l15][kt * 32 + quad * 8];
        const half8 xB0 = *(const half8*)&Xs1[l15][kt * 32 + quad * 8];
        const half8 xB1 = *(const half8*)&Xs1[16 + l15][kt * 32 + quad * 8];
        #pragma unroll
        for (int nt = 0; nt < 4; ++nt) {
            const half8 wf = *(const half8*)(w1w + (kt * 16 + nt) * 512 + lo8);
            acc[0][0][nt] = __builtin_amdgcn_mfma_f32_16x16x32_f16(wf, xA0, acc[0][0][nt], 0, 0, 0);
            acc[0][1][nt] = __builtin_amdgcn_mfma_f32_16x16x32_f16(wf, xA1, acc[0][1][nt], 0, 0, 0);
            acc[1][0][nt] = __builtin_amdgcn_mfma_f32_16x16x32_f16(wf, xB0, acc[1][0][nt], 0, 0, 0);
            acc[1][1][nt] = __builtin_amdgcn_mfma_f32_16x16x32_f16(wf, xB1, acc[1][1][nt], 0, 0, 0);
        }
    }
    __builtin_amdgcn_s_setprio(0);

    // ---- LN1 stats: packed pairwise accumulate + quad shfl + cross-warp LDS ----
    float mu[2][2], rs[2][2];
    #pragma unroll
    for (int qq = 0; qq < 2; ++qq)
        #pragma unroll
        for (int mt = 0; mt < 2; ++mt) {
            f32x2 sx  = {0.f, 0.f};
            f32x2 s2x = {0.f, 0.f};
            #pragma unroll
            for (int nt = 0; nt < 4; ++nt) {
                const f32x4 a4 = acc[qq][mt][nt];
                const f32x2 v0 = __builtin_shufflevector(a4, a4, 0, 1);
                const f32x2 v1 = __builtin_shufflevector(a4, a4, 2, 3);
                sx  = sx + v0;
                sx  = sx + v1;
                s2x = pkfma(v0, v0, s2x);
                s2x = pkfma(v1, v1, s2x);
            }
            float s  = sx.x + sx.y;
            float s2 = s2x.x + s2x.y;
            s  += __shfl_xor(s, 16, 64);  s  += __shfl_xor(s, 32, 64);
            s2 += __shfl_xor(s2, 16, 64); s2 += __shfl_xor(s2, 32, 64);
            if (quad == 0) sred[qq][mt][l15][w] = make_float2(s, s2);
        }
    __syncthreads();   // overlay fence (Xs reads done) + sred partials visible
    #pragma unroll
    for (int qq = 0; qq < 2; ++qq)
        #pragma unroll
        for (int mt = 0; mt < 2; ++mt) {
            const float4 pA = *(const float4*)&sred[qq][mt][l15][0];
            const float4 pB = *(const float4*)&sred[qq][mt][l15][2];
            const float S = pA.x + pA.z + pB.x + pB.z;
            const float Q = pA.y + pA.w + pB.y + pB.w;
            const float m_ = S * (1.0f / 256.0f);
            const float var = fmaf(Q, 1.0f / 256.0f, -m_ * m_);
            mu[qq][mt] = m_;
            rs[qq][mt] = __builtin_amdgcn_rsqf(var + 1e-5f);
        }

    // ---- LN1 apply + GeLU, packed f32, single f16 store into H16 ----
    #pragma unroll
    for (int nt = 0; nt < 4; ++nt) {
        const int chb = (w * 4 + nt) * 16 + quad * 4;
        const f32x2 gf0 = *(const f32x2*)&g1f[chb];
        const f32x2 gf1 = *(const f32x2*)&g1f[chb + 2];
        const f32x2 bf0 = *(const f32x2*)&be1f[chb];
        const f32x2 bf1 = *(const f32x2*)&be1f[chb + 2];
        #pragma unroll
        for (int qq = 0; qq < 2; ++qq)
            #pragma unroll
            for (int mt = 0; mt < 2; ++mt) {
                const f32x2 rs2  = {rs[qq][mt], rs[qq][mt]};
                const f32x2 nmu2 = {-mu[qq][mt], -mu[qq][mt]};
                const f32x2 A0 = gf0 * rs2;
                const f32x2 A1 = gf1 * rs2;
                const f32x2 B0 = pkfma(nmu2, A0, bf0);
                const f32x2 B1 = pkfma(nmu2, A1, bf1);
                const f32x4 a4 = acc[qq][mt][nt];
                const f32x2 y0 = pkfma(__builtin_shufflevector(a4, a4, 0, 1), A0, B0);
                const f32x2 y1 = pkfma(__builtin_shufflevector(a4, a4, 2, 3), A1, B1);
                const f32x2 o0 = gelu2(y0);
                const f32x2 o1 = gelu2(y1);
                half4v h;
                h[0] = (_Float16)o0.x; h[1] = (_Float16)o0.y;
                h[2] = (_Float16)o1.x; h[3] = (_Float16)o1.y;
                if (qq == 0) *(half4v*)&H16a[mt * 16 + l15][chb] = h;
                else         *(half4v*)&H16b[mt * 16 + l15][chb] = h;
            }
    }
    __syncthreads();   // H16 ready for GEMM2 B-reads

    // b2 fragments for GEMM2 C-init (short live range: load here, die at init)
    f32x4 bv[4];
    #pragma unroll
    for (int nt = 0; nt < 4; ++nt)
        bv[nt] = *(const f32x4*)&b2[(w * 4 + nt) * 16 + quad * 4];

    // ---- GEMM2: W2^T as A, H{a,b} as B; C-init = b2 (fold) ----
    #pragma unroll
    for (int qq = 0; qq < 2; ++qq)
        #pragma unroll
        for (int mt = 0; mt < 2; ++mt)
            #pragma unroll
            for (int nt = 0; nt < 4; ++nt)
                acc[qq][mt][nt] = bv[nt];

    __builtin_amdgcn_s_setprio(1);
    #pragma unroll
    for (int kt = 0; kt < 8; ++kt) {
        const half8 hA0 = *(const half8*)&H16a[l15][kt * 32 + quad * 8];
        const half8 hA1 = *(const half8*)&H16a[16 + l15][kt * 32 + quad * 8];
        const half8 hB0 = *(const half8*)&H16b[l15][kt * 32 + quad * 8];
        const half8 hB1 = *(const half8*)&H16b[16 + l15][kt * 32 + quad * 8];
        #pragma unroll
        for (int nt = 0; nt < 4; ++nt) {
            const half8 wf = *(const half8*)(w2w + (kt * 16 + nt) * 512 + lo8);
            acc[0][0][nt] = __builtin_amdgcn_mfma_f32_16x16x32_f16(wf, hA0, acc[0][0][nt], 0, 0, 0);
            acc[0][1][nt] = __builtin_amdgcn_mfma_f32_16x16x32_f16(wf, hA1, acc[0][1][nt], 0, 0, 0);
            acc[1][0][nt] = __builtin_amdgcn_mfma_f32_16x16x32_f16(wf, hB0, acc[1][0][nt], 0, 0, 0);
            acc[1][1][nt] = __builtin_amdgcn_mfma_f32_16x16x32_f16(wf, hB1, acc[1][1][nt], 0, 0, 0);
        }
    }
    __builtin_amdgcn_s_setprio(0);

    // ---- LN2 stats: packed pairwise (b2 already folded in) ----
    #pragma unroll
    for (int qq = 0; qq < 2; ++qq)
        #pragma unroll
        for (int mt = 0; mt < 2; ++mt) {
            f32x2 sx  = {0.f, 0.f};
            f32x2 s2x = {0.f, 0.f};
            #pragma unroll
            for (int nt = 0; nt < 4; ++nt) {
                const f32x4 a4 = acc[qq][mt][nt];
                const f32x2 v0 = __builtin_shufflevector(a4, a4, 0, 1);
                const f32x2 v1 = __builtin_shufflevector(a4, a4, 2, 3);
                sx  = sx + v0;
                sx  = sx + v1;
                s2x = pkfma(v0, v0, s2x);
                s2x = pkfma(v1, v1, s2x);
            }
            float s  = sx.x + sx.y;
            float s2 = s2x.x + s2x.y;
            s  += __shfl_xor(s, 16, 64);  s  += __shfl_xor(s, 32, 64);
            s2 += __shfl_xor(s2, 16, 64); s2 += __shfl_xor(s2, 32, 64);
            if (quad == 0) sred[qq][mt][l15][w] = make_float2(s, s2);
        }
    __syncthreads();   // ALL H16 B-reads done (in-place store safe) + partials
    #pragma unroll
    for (int qq = 0; qq < 2; ++qq)
        #pragma unroll
        for (int mt = 0; mt < 2; ++mt) {
            const float4 pA = *(const float4*)&sred[qq][mt][l15][0];
            const float4 pB = *(const float4*)&sred[qq][mt][l15][2];
            const float S = pA.x + pA.z + pB.x + pB.z;
            const float Q = pA.y + pA.w + pB.y + pB.w;
            const float m_ = S * (1.0f / 256.0f);
            const float var = fmaf(Q, 1.0f / 256.0f, -m_ * m_);
            mu[qq][mt] = m_;
            rs[qq][mt] = __builtin_amdgcn_rsqf(var + 1e-5f);
        }

    // ---- LN2 apply (no activation), packed f32, f16 store into H16 ----
    #pragma unroll
    for (int nt = 0; nt < 4; ++nt) {
        const int chb = (w * 4 + nt) * 16 + quad * 4;
        const f32x2 gf0 = *(const f32x2*)&g2f[chb];
        const f32x2 gf1 = *(const f32x2*)&g2f[chb + 2];
        const f32x2 bf0 = *(const f32x2*)&be2f[chb];
        const f32x2 bf1 = *(const f32x2*)&be2f[chb + 2];
        #pragma unroll
        for (int qq = 0; qq < 2; ++qq)
            #pragma unroll
            for (int mt = 0; mt < 2; ++mt) {
                const f32x2 rs2  = {rs[qq][mt], rs[qq][mt]};
                const f32x2 nmu2 = {-mu[qq][mt], -mu[qq][mt]};
                const f32x2 A0 = gf0 * rs2;
                const f32x2 A1 = gf1 * rs2;
                const f32x2 B0 = pkfma(nmu2, A0, bf0);
                const f32x2 B1 = pkfma(nmu2, A1, bf1);
                const f32x4 a4 = acc[qq][mt][nt];
                const f32x2 y0 = pkfma(__builtin_shufflevector(a4, a4, 0, 1), A0, B0);
                const f32x2 y1 = pkfma(__builtin_shufflevector(a4, a4, 2, 3), A1, B1);
                half4v h;
                h[0] = (_Float16)y0.x; h[1] = (_Float16)y0.y;
                h[2] = (_Float16)y1.x; h[3] = (_Float16)y1.y;
                if (qq == 0) *(half4v*)&H16a[mt * 16 + l15][chb] = h;
                else         *(half4v*)&H16b[mt * 16 + l15][chb] = h;
            }
    }
    __syncthreads();

    // ---- Phase 6: packed max over 32 points, all 256 threads (2 queries) ----
    {
        const int qq = t >> 7;
        const int tt = t & 127;
        const _Float16* Hf = qq ? &H16b[0][0] : &H16a[0][0];
        half2t mx = *(const half2t*)(Hf + 2 * tt);
        #pragma unroll
        for (int r = 1; r < KN; ++r) {
            const half2t v = *(const half2t*)(Hf + r * HSTR + 2 * tt);
            mx = __builtin_elementwise_max(mx, v);
        }
        float2 o2;
        o2.x = (float)mx[0];
        o2.y = (float)mx[1];
        *(float2*)&out0[(size_t)(q0 + qq) * C + 2 * tt] = o2;
    }
}

extern "C" void kernel_launch(void* const* d_in, const int* in_sizes, int n_in,
                              void* d_out, int out_size, void* d_ws, size_t ws_size,
                              hipStream_t stream) {
    const float* xyz = (const float*)d_in[0];
    const float* pf  = (const float*)d_in[1];
    const float* ctr = (const float*)d_in[2];
    const float* W1  = (const float*)d_in[3];
    const float* b1  = (const float*)d_in[4];
    const float* g1  = (const float*)d_in[5];
    const float* be1 = (const float*)d_in[6];
    const float* W2  = (const float*)d_in[7];
    const float* b2  = (const float*)d_in[8];
    const float* g2  = (const float*)d_in[9];
    const float* be2 = (const float*)d_in[10];

    float* out = (float*)d_out;
    _Float16* wp = (_Float16*)d_ws;
    float4* xyzw = (float4*)(wp + WP_ELEMS);   // 180224 B offset, 16-aligned; +2.06 MB

    prep_kernel<<<(WP_ELEMS + XYZW_ELEMS) / 256, 256, 0, stream>>>(W1, b1, W2, xyz, wp, xyzw);
    encoder_fused<<<NQ / 2, 256, 0, stream>>>(xyzw, pf, ctr,
                                              g1, be1, b2, g2, be2,
                                              wp, wp + W1P_ELEMS,
                                              out, out + PF_ELEMS);
}